// Round 9
// baseline (324.756 us; speedup 1.0000x reference)
//
#include <hip/hip_runtime.h>
#include <hip/hip_bf16.h>

#define NNODES 100000
#define NEDGES 20000
#define NPINS  1600000

// coarse binning: 64 edges per bucket, 128 nodes per bucket
#define EB_SHIFT 6
#define NB_SHIFT 7
#define NB_E ((NEDGES + 63) / 64)      // 313
#define NB_N ((NNODES + 127) / 128)    // 782
#define NB_TOT (NB_E + NB_N)           // 1095
// fixed-capacity bucket regions (mean edge bucket = 5120 pins, node = 2048)
#define ECAP 6144
#define NCAP 2560
#define REG_TOTAL (NB_E * ECAP + NB_N * NCAP)   // 3,924,992

typedef __attribute__((ext_vector_type(8))) short short8;
typedef __attribute__((ext_vector_type(4))) float f32x4;
typedef unsigned int uint;

// ---------------- bf16 helpers ----------------

static __device__ inline float bf_lo(uint u) { return __uint_as_float(u << 16); }
static __device__ inline float bf_hi(uint u) { return __uint_as_float(u & 0xffff0000u); }

static __device__ inline uint pack_bf2(float a, float b) {
    union { __hip_bfloat16 h; unsigned short u; } ua, ub;
    ua.h = __float2bfloat16(a);
    ub.h = __float2bfloat16(b);
    return ((uint)ub.u << 16) | (uint)ua.u;
}

// ---------------- CSR construction (binned counting sort, packed uint pairs) ----------------
// packed pair: (local_key << 20) | value   (local_key <= 7 bits, value < 2^17)

__global__ void bin_scatter(const int* __restrict__ he, int* __restrict__ ccnt,
                            uint* __restrict__ pairs) {
    __shared__ int hcnt[NB_TOT];
    __shared__ int hbase[NB_TOT];
    int tid = threadIdx.x;
    int base = blockIdx.x * 8192;
    for (int j = tid; j < NB_TOT; j += 256) hcnt[j] = 0;
    __syncthreads();
    for (int k = 0; k < 32; k++) {
        int i = base + k * 256 + tid;
        if (i < NPINS) {
            int n = he[i];
            int e = he[NPINS + i];
            atomicAdd(&hcnt[e >> EB_SHIFT], 1);
            atomicAdd(&hcnt[NB_E + (n >> NB_SHIFT)], 1);
        }
    }
    __syncthreads();
    for (int j = tid; j < NB_TOT; j += 256)
        hbase[j] = hcnt[j] ? atomicAdd(&ccnt[j], hcnt[j]) : 0;
    __syncthreads();
    for (int k = 0; k < 32; k++) {
        int i = base + k * 256 + tid;
        if (i < NPINS) {
            int n = he[i];
            int e = he[NPINS + i];
            int be = e >> EB_SHIFT;
            int pe = atomicAdd(&hbase[be], 1);
            if (pe < ECAP)
                pairs[be * ECAP + pe] = ((uint)(e & 63) << 20) | (uint)n;
            int bn = n >> NB_SHIFT;
            int pn = atomicAdd(&hbase[NB_E + bn], 1);
            if (pn < NCAP)
                pairs[NB_E * ECAP + bn * NCAP + pn] = ((uint)(n & 127) << 20) | (uint)e;
        }
    }
}

// single register-staged read of pairs; LDS hist; LDS cursor placement
template <int KPB, int CAP>
__global__ void bucket_place(const uint* __restrict__ pairs, int regbase,
                             const int* __restrict__ ccnt, int cbase, int kfine_base, int nkeys,
                             int* __restrict__ off, int* __restrict__ cnt,
                             int* __restrict__ pins) {
    constexpr int NIT = CAP / 256;
    __shared__ int fh[KPB];
    __shared__ int fo[KPB];
    __shared__ int fcur[KPB];
    int b = blockIdx.x;
    int tid = threadIdx.x;
    int rb = regbase + b * CAP;
    int count = ccnt[cbase + b];
    if (count > CAP) count = CAP;
    int keyfirst = b * KPB;
    uint pr[NIT];
    for (int k = tid; k < KPB; k += 256) { fh[k] = 0; fcur[k] = 0; }
#pragma unroll
    for (int i = 0; i < NIT; i++) {
        int idx = tid + i * 256;
        if (idx < count) pr[i] = pairs[rb + idx];
    }
    __syncthreads();
#pragma unroll
    for (int i = 0; i < NIT; i++) {
        int idx = tid + i * 256;
        if (idx < count) atomicAdd(&fh[pr[i] >> 20], 1);
    }
    __syncthreads();
    if (tid == 0) {
        int run = rb;
        for (int k = 0; k < KPB; k++) { fo[k] = run; run += fh[k]; }
    }
    __syncthreads();
    for (int k = tid; k < KPB; k += 256) {
        int key = keyfirst + k;
        if (key < nkeys) { off[kfine_base + key] = fo[k]; cnt[kfine_base + key] = fh[k]; }
    }
#pragma unroll
    for (int i = 0; i < NIT; i++) {
        int idx = tid + i * 256;
        if (idx < count) {
            uint p = pr[i];
            int kl = (int)(p >> 20);
            int pos = atomicAdd(&fcur[kl], 1);
            pins[fo[kl] + pos] = (int)(p & 0xFFFFFu);
        }
    }
}

// ---------------- MFMA GEMM: Yb[nrows,COLS](bf16) = X[nrows,128] @ W[128,COLS] ----------------

template <int COLS, bool BF16IN>
__global__ void gemm_mfma(const void* __restrict__ Xv, const float* __restrict__ W,
                          unsigned short* __restrict__ Yb) {
    __shared__ __align__(16) char lds[128 * 256 + COLS * 256];
    char* Xl = lds;                 // [128 rows][128 k] bf16, XOR-swizzled
    char* Wt = lds + 128 * 256;     // [COLS cols][128 k] bf16, swizzled
    int tid = threadIdx.x;
    long rowbase = (long)blockIdx.x * 128;

    if constexpr (!BF16IN) {
        const float4* X4 = reinterpret_cast<const float4*>(Xv);
#pragma unroll
        for (int i = 0; i < 16; i++) {
            int f = tid + i * 256;
            int r = f >> 5;
            int c4 = f & 31;
            long gr = rowbase + r;
            if (gr > NNODES - 1) gr = NNODES - 1;
            float4 v = X4[gr * 32 + c4];
            uint lo = pack_bf2(v.x, v.y);
            uint hi = pack_bf2(v.z, v.w);
            int byte = r * 256 + ((c4 * 8) ^ ((r & 7) << 4));
            *reinterpret_cast<uint2*>(Xl + byte) = make_uint2(lo, hi);
        }
    } else {
        const uint4* X4 = reinterpret_cast<const uint4*>(Xv);
#pragma unroll
        for (int i = 0; i < 8; i++) {
            int f = tid + i * 256;
            int r = f >> 4;
            int c = f & 15;
            long gr = rowbase + r;
            if (gr > NNODES - 1) gr = NNODES - 1;
            uint4 v = X4[gr * 16 + c];
            int byte = r * 256 + ((c * 16) ^ ((r & 7) << 4));
            *reinterpret_cast<uint4*>(Xl + byte) = v;
        }
    }
    for (int f = tid; f < 128 * COLS / 4; f += 256) {
        int k = f / (COLS / 4);
        int c4 = f % (COLS / 4);
        float4 v = reinterpret_cast<const float4*>(W)[f];
        float vv[4] = {v.x, v.y, v.z, v.w};
#pragma unroll
        for (int j = 0; j < 4; j++) {
            int c = c4 * 4 + j;
            union { __hip_bfloat16 h; short s; } u;
            u.h = __float2bfloat16(vv[j]);
            int byte = c * 256 + ((k * 2) ^ ((c & 7) << 4));
            *reinterpret_cast<short*>(Wt + byte) = u.s;
        }
    }
    __syncthreads();

    constexpr int NF = COLS / 16;
    int wave = tid >> 6;
    int lane = tid & 63;
    int lrow = lane & 15;
    int lq = lane >> 4;
    f32x4 acc[2][NF] = {};

#pragma unroll
    for (int ks = 0; ks < 4; ks++) {
        short8 a[2];
#pragma unroll
        for (int rt = 0; rt < 2; rt++) {
            int r = wave * 32 + rt * 16 + lrow;
            int byte = r * 256 + ((ks * 64 + lq * 16) ^ ((r & 7) << 4));
            a[rt] = *reinterpret_cast<const short8*>(Xl + byte);
        }
#pragma unroll
        for (int nf = 0; nf < NF; nf++) {
            int c = nf * 16 + lrow;
            int byte = c * 256 + ((ks * 64 + lq * 16) ^ ((c & 7) << 4));
            short8 b = *reinterpret_cast<const short8*>(Wt + byte);
            acc[0][nf] = __builtin_amdgcn_mfma_f32_16x16x32_bf16(a[0], b, acc[0][nf], 0, 0, 0);
            acc[1][nf] = __builtin_amdgcn_mfma_f32_16x16x32_bf16(a[1], b, acc[1][nf], 0, 0, 0);
        }
    }

#pragma unroll
    for (int rt = 0; rt < 2; rt++)
#pragma unroll
        for (int nf = 0; nf < NF; nf++)
#pragma unroll
            for (int r = 0; r < 4; r++) {
                long row = rowbase + wave * 32 + rt * 16 + lq * 4 + r;
                if (row < NNODES) {
                    union { __hip_bfloat16 h; unsigned short u; } u;
                    u.h = __float2bfloat16(acc[rt][nf][r]);
                    Yb[row * COLS + nf * 16 + lrow] = u.u;
                }
            }
}

// ---------------- aggregation (bf16 features, fp32 accumulate) ----------------

#define ACC_U2(u) do { \
    a0 += bf_lo((u).x); a1 += bf_hi((u).x); a2 += bf_lo((u).y); a3 += bf_hi((u).y); } while (0)

// F=128 edge aggregation: half-wave per pin, 8-pin chunks
__global__ void edge_agg_128(const uint2* __restrict__ feat2, const int* __restrict__ pins,
                             const int* __restrict__ off, const int* __restrict__ cnt,
                             uint2* __restrict__ outp) {
    int s = blockIdx.x * 4 + (threadIdx.x >> 6);
    if (s >= NEDGES) return;
    int lane = threadIdx.x & 63;
    int half = lane >> 5, fp = lane & 31;
    int start = off[s], c = cnt[s];
    float a0 = 0.f, a1 = 0.f, a2 = 0.f, a3 = 0.f;
    for (int cb = 0; cb < c; cb += 64) {
        int rem = c - cb;
        int lim = rem < 64 ? rem : 64;
        int pk = 0;
        if (lane < lim) pk = pins[start + cb + lane];
        int i = 0;
        for (; i + 8 <= lim; i += 8) {
            int pa = __shfl(pk, i + half);
            int pb = __shfl(pk, i + 2 + half);
            int pc = __shfl(pk, i + 4 + half);
            int pd = __shfl(pk, i + 6 + half);
            uint2 ua = feat2[(uint)pa * 32 + fp];
            uint2 ub = feat2[(uint)pb * 32 + fp];
            uint2 uc = feat2[(uint)pc * 32 + fp];
            uint2 ud = feat2[(uint)pd * 32 + fp];
            ACC_U2(ua); ACC_U2(ub); ACC_U2(uc); ACC_U2(ud);
        }
        for (; i + 2 <= lim; i += 2) {
            int p = __shfl(pk, i + half);
            uint2 u = feat2[(uint)p * 32 + fp];
            ACC_U2(u);
        }
        if (i < lim) {
            int p = __shfl(pk, i);
            if (half == 0) {
                uint2 u = feat2[(uint)p * 32 + fp];
                ACC_U2(u);
            }
        }
    }
    a0 += __shfl_xor(a0, 32); a1 += __shfl_xor(a1, 32);
    a2 += __shfl_xor(a2, 32); a3 += __shfl_xor(a3, 32);
    if (half == 0) {
        float inv = (c > 0) ? (1.f / (float)c) : 0.f;
        outp[(uint)s * 32 + fp] = make_uint2(pack_bf2(a0 * inv, a1 * inv),
                                             pack_bf2(a2 * inv, a3 * inv));
    }
}

// node conv1 aggregation, feature-half phase: gathers 128 B half-rows of mb (2.56 MB
// working set -> per-XCD L2 resident). Writes exact fp32 v (agg*dinv + b1) to vtmp.
template <int PHASE>
__global__ void node_agg_phase(const uint2* __restrict__ mb2, const int* __restrict__ pins,
                               const int* __restrict__ off, const int* __restrict__ cnt,
                               const float* __restrict__ b1, float4* __restrict__ vtmp) {
    int s = blockIdx.x * 4 + (threadIdx.x >> 6);
    if (s >= NNODES) return;
    int lane = threadIdx.x & 63;
    int q = lane >> 4, fp = lane & 15;
    int start = off[s], c = cnt[s];
    float a0 = 0.f, a1 = 0.f, a2 = 0.f, a3 = 0.f;
    for (int cb = 0; cb < c; cb += 64) {
        int rem = c - cb;
        int lim = rem < 64 ? rem : 64;
        int pk = 0;
        if (lane < lim) pk = pins[start + cb + lane];
        int i = 0;
        for (; i + 16 <= lim; i += 16) {
            int pa = __shfl(pk, i + q);
            int pb = __shfl(pk, i + 4 + q);
            int pc = __shfl(pk, i + 8 + q);
            int pd = __shfl(pk, i + 12 + q);
            uint2 ua = mb2[(uint)pa * 32 + PHASE * 16 + fp];
            uint2 ub = mb2[(uint)pb * 32 + PHASE * 16 + fp];
            uint2 uc = mb2[(uint)pc * 32 + PHASE * 16 + fp];
            uint2 ud = mb2[(uint)pd * 32 + PHASE * 16 + fp];
            ACC_U2(ua); ACC_U2(ub); ACC_U2(uc); ACC_U2(ud);
        }
        for (; i + 4 <= lim; i += 4) {
            int p = __shfl(pk, i + q);
            uint2 u = mb2[(uint)p * 32 + PHASE * 16 + fp];
            ACC_U2(u);
        }
        if (i < lim) {
            int idx = i + q;
            int p = __shfl(pk, idx < lim ? idx : i);
            if (idx < lim) {
                uint2 u = mb2[(uint)p * 32 + PHASE * 16 + fp];
                ACC_U2(u);
            }
        }
    }
    a0 += __shfl_xor(a0, 16); a1 += __shfl_xor(a1, 16);
    a2 += __shfl_xor(a2, 16); a3 += __shfl_xor(a3, 16);
    a0 += __shfl_xor(a0, 32); a1 += __shfl_xor(a1, 32);
    a2 += __shfl_xor(a2, 32); a3 += __shfl_xor(a3, 32);
    if (lane < 16) {
        float dinv = (c > 0) ? (1.f / (float)c) : 0.f;
        float4 bb = reinterpret_cast<const float4*>(b1)[PHASE * 16 + fp];
        vtmp[(uint)s * 32 + PHASE * 16 + fp] =
            make_float4(a0 * dinv + bb.x, a1 * dinv + bb.y,
                        a2 * dinv + bb.z, a3 * dinv + bb.w);
    }
}

// streaming LN + LeakyReLU: half-wave per node, lane holds 4 features (fp32, exact)
__global__ void ln_apply(const float4* __restrict__ vtmp, const float* __restrict__ gamma,
                         const float* __restrict__ beta, uint2* __restrict__ hout) {
    int s = blockIdx.x * 8 + (threadIdx.x >> 5);
    if (s >= NNODES) return;
    int l = threadIdx.x & 31;
    float4 v = vtmp[(uint)s * 32 + l];
    float sum = (v.x + v.y) + (v.z + v.w);
    float sq = (v.x * v.x + v.y * v.y) + (v.z * v.z + v.w * v.w);
#pragma unroll
    for (int o = 1; o < 32; o <<= 1) {
        sum += __shfl_xor(sum, o);
        sq  += __shfl_xor(sq, o);
    }
    float mu = sum * (1.f / 128.f);
    float var = sq * (1.f / 128.f) - mu * mu;
    float rstd = rsqrtf(var + 1e-5f);
    float4 g  = reinterpret_cast<const float4*>(gamma)[l];
    float4 be = reinterpret_cast<const float4*>(beta)[l];
    float h0 = (v.x - mu) * rstd * g.x + be.x;
    float h1 = (v.y - mu) * rstd * g.y + be.y;
    float h2 = (v.z - mu) * rstd * g.z + be.z;
    float h3 = (v.w - mu) * rstd * g.w + be.w;
    h0 = (h0 > 0.f) ? h0 : 0.01f * h0;
    h1 = (h1 > 0.f) ? h1 : 0.01f * h1;
    h2 = (h2 > 0.f) ? h2 : 0.01f * h2;
    h3 = (h3 > 0.f) ? h3 : 0.01f * h3;
    hout[(uint)s * 32 + l] = make_uint2(pack_bf2(h0, h1), pack_bf2(h2, h3));
}

// F=64 edge aggregation: quarter-wave per pin, 16-pin chunks
__global__ void edge_agg_64(const uint2* __restrict__ feat2, const int* __restrict__ pins,
                            const int* __restrict__ off, const int* __restrict__ cnt,
                            uint2* __restrict__ outp) {
    int s = blockIdx.x * 4 + (threadIdx.x >> 6);
    if (s >= NEDGES) return;
    int lane = threadIdx.x & 63;
    int q = lane >> 4, fp = lane & 15;
    int start = off[s], c = cnt[s];
    float a0 = 0.f, a1 = 0.f, a2 = 0.f, a3 = 0.f;
    for (int cb = 0; cb < c; cb += 64) {
        int rem = c - cb;
        int lim = rem < 64 ? rem : 64;
        int pk = 0;
        if (lane < lim) pk = pins[start + cb + lane];
        int i = 0;
        for (; i + 16 <= lim; i += 16) {
            int pa = __shfl(pk, i + q);
            int pb = __shfl(pk, i + 4 + q);
            int pc = __shfl(pk, i + 8 + q);
            int pd = __shfl(pk, i + 12 + q);
            uint2 ua = feat2[(uint)pa * 16 + fp];
            uint2 ub = feat2[(uint)pb * 16 + fp];
            uint2 uc = feat2[(uint)pc * 16 + fp];
            uint2 ud = feat2[(uint)pd * 16 + fp];
            ACC_U2(ua); ACC_U2(ub); ACC_U2(uc); ACC_U2(ud);
        }
        for (; i + 4 <= lim; i += 4) {
            int p = __shfl(pk, i + q);
            uint2 u = feat2[(uint)p * 16 + fp];
            ACC_U2(u);
        }
        if (i < lim) {
            int idx = i + q;
            int p = __shfl(pk, idx < lim ? idx : i);
            if (idx < lim) {
                uint2 u = feat2[(uint)p * 16 + fp];
                ACC_U2(u);
            }
        }
    }
    a0 += __shfl_xor(a0, 16); a1 += __shfl_xor(a1, 16);
    a2 += __shfl_xor(a2, 16); a3 += __shfl_xor(a3, 16);
    a0 += __shfl_xor(a0, 32); a1 += __shfl_xor(a1, 32);
    a2 += __shfl_xor(a2, 32); a3 += __shfl_xor(a3, 32);
    if (lane < 16) {
        float inv = (c > 0) ? (1.f / (float)c) : 0.f;
        outp[(uint)s * 16 + fp] = make_uint2(pack_bf2(a0 * inv, a1 * inv),
                                             pack_bf2(a2 * inv, a3 * inv));
    }
}

__global__ void node_agg_out(const uint2* __restrict__ m2, const int* __restrict__ pins,
                             const int* __restrict__ off, const int* __restrict__ cnt,
                             const float* __restrict__ b3, float4* __restrict__ out4) {
    int s = blockIdx.x * 4 + (threadIdx.x >> 6);
    if (s >= NNODES) return;
    int lane = threadIdx.x & 63;
    int q = lane >> 4, fp = lane & 15;
    int start = off[s], c = cnt[s];
    float a0 = 0.f, a1 = 0.f, a2 = 0.f, a3 = 0.f;
    for (int cb = 0; cb < c; cb += 64) {
        int rem = c - cb;
        int lim = rem < 64 ? rem : 64;
        int pk = 0;
        if (lane < lim) pk = pins[start + cb + lane];
        int i = 0;
        for (; i + 16 <= lim; i += 16) {
            int pa = __shfl(pk, i + q);
            int pb = __shfl(pk, i + 4 + q);
            int pc = __shfl(pk, i + 8 + q);
            int pd = __shfl(pk, i + 12 + q);
            uint2 ua = m2[(uint)pa * 16 + fp];
            uint2 ub = m2[(uint)pb * 16 + fp];
            uint2 uc = m2[(uint)pc * 16 + fp];
            uint2 ud = m2[(uint)pd * 16 + fp];
            ACC_U2(ua); ACC_U2(ub); ACC_U2(uc); ACC_U2(ud);
        }
        for (; i + 4 <= lim; i += 4) {
            int p = __shfl(pk, i + q);
            uint2 u = m2[(uint)p * 16 + fp];
            ACC_U2(u);
        }
        if (i < lim) {
            int idx = i + q;
            int p = __shfl(pk, idx < lim ? idx : i);
            if (idx < lim) {
                uint2 u = m2[(uint)p * 16 + fp];
                ACC_U2(u);
            }
        }
    }
    a0 += __shfl_xor(a0, 16); a1 += __shfl_xor(a1, 16);
    a2 += __shfl_xor(a2, 16); a3 += __shfl_xor(a3, 16);
    a0 += __shfl_xor(a0, 32); a1 += __shfl_xor(a1, 32);
    a2 += __shfl_xor(a2, 32); a3 += __shfl_xor(a3, 32);
    if (lane < 16) {
        float inv = (c > 0) ? (1.f / (float)c) : 0.f;
        float4 bb = reinterpret_cast<const float4*>(b3)[fp];
        out4[(uint)s * 16 + fp] = make_float4(a0 * inv + bb.x, a1 * inv + bb.y,
                                              a2 * inv + bb.z, a3 * inv + bb.w);
    }
}

// ---------------- launch ----------------

extern "C" void kernel_launch(void* const* d_in, const int* in_sizes, int n_in,
                              void* d_out, int out_size, void* d_ws, size_t ws_size,
                              hipStream_t stream) {
    const float* x     = (const float*)d_in[0];
    const int*   he    = (const int*)d_in[1];
    const float* W1    = (const float*)d_in[2];
    const float* b1    = (const float*)d_in[3];
    const float* gamma = (const float*)d_in[4];
    const float* beta  = (const float*)d_in[5];
    const float* W3    = (const float*)d_in[6];
    const float* b3    = (const float*)d_in[7];
    float* out = (float*)d_out;

    char* ws = (char*)d_ws;
    uint* xWb = (uint*)ws;                                  // 25.6 MB bf16 (hWb 12.8 MB overlay)
    uint* mb  = (uint*)(ws + 25600000);                     // 5.12 MB bf16 (m2b 2.56 MB overlay)
    uint* hb  = (uint*)(ws + 25600000 + 5120000);           // 25.6 MB bf16
    char* ip  = ws + 25600000 + 5120000 + 25600000;
    int* off  = (int*)ip;                   // NEDGES+NNODES
    int* cnt  = off + (NEDGES + NNODES);
    int* ccnt = cnt + (NEDGES + NNODES);    // NB_TOT
    int* pins = ccnt + NB_TOT + 64;         // REG_TOTAL ints
    float4* vtmp = (float4*)(ws + 73000000);  // 51.2 MB fp32 [NNODES][32]
    uint* pairs = (uint*)ws;                // 15.7 MB overlay, dead before gemm1

    const int nblkA = (NPINS + 8191) / 8192;   // 196
    const int ngemm = (NNODES + 127) / 128;    // 782

    hipMemsetAsync(ccnt, 0, sizeof(int) * NB_TOT, stream);
    bin_scatter<<<nblkA, 256, 0, stream>>>(he, ccnt, pairs);
    bucket_place<64, ECAP><<<NB_E, 256, 0, stream>>>(pairs, 0, ccnt, 0, 0, NEDGES,
                                                     off, cnt, pins);
    bucket_place<128, NCAP><<<NB_N, 256, 0, stream>>>(pairs, NB_E * ECAP, ccnt, NB_E,
                                                      NEDGES, NNODES, off, cnt, pins);

    // conv1: xWb = bf16(x @ W1); edge agg; node agg (2 feature-half phases) + LN apply
    gemm_mfma<128, false><<<ngemm, 256, 0, stream>>>(x, W1, (unsigned short*)xWb);
    edge_agg_128<<<(NEDGES + 3) / 4, 256, 0, stream>>>((const uint2*)xWb, pins, off, cnt,
                                                       (uint2*)mb);
    node_agg_phase<0><<<(NNODES + 3) / 4, 256, 0, stream>>>((const uint2*)mb, pins,
                                                            off + NEDGES, cnt + NEDGES,
                                                            b1, vtmp);
    node_agg_phase<1><<<(NNODES + 3) / 4, 256, 0, stream>>>((const uint2*)mb, pins,
                                                            off + NEDGES, cnt + NEDGES,
                                                            b1, vtmp);
    ln_apply<<<(NNODES + 7) / 8, 256, 0, stream>>>(vtmp, gamma, beta, (uint2*)hb);

    // conv2: hWb = bf16(h @ W3) (reuse xWb); edge agg (reuse mb); node agg -> out
    gemm_mfma<64, true><<<ngemm, 256, 0, stream>>>(hb, W3, (unsigned short*)xWb);
    edge_agg_64<<<(NEDGES + 3) / 4, 256, 0, stream>>>((const uint2*)xWb, pins, off, cnt,
                                                      (uint2*)mb);
    node_agg_out<<<(NNODES + 3) / 4, 256, 0, stream>>>((const uint2*)mb, pins, off + NEDGES,
                                                       cnt + NEDGES, b3, (float4*)out);
}

// Round 10
// 290.997 us; speedup vs baseline: 1.1160x; 1.1160x over previous
//
#include <hip/hip_runtime.h>
#include <hip/hip_bf16.h>

#define NNODES 100000
#define NEDGES 20000
#define NPINS  1600000

// coarse binning: 64 edges per bucket, 128 nodes per bucket
#define EB_SHIFT 6
#define NB_SHIFT 7
#define NB_E ((NEDGES + 63) / 64)      // 313
#define NB_N ((NNODES + 127) / 128)    // 782
#define NB_TOT (NB_E + NB_N)           // 1095
// fixed-capacity bucket regions (mean edge bucket = 5120 pins, node = 2048)
#define ECAP 6144
#define NCAP 2560
#define REG_TOTAL (NB_E * ECAP + NB_N * NCAP)   // 3,924,992

typedef __attribute__((ext_vector_type(8))) short short8;
typedef __attribute__((ext_vector_type(4))) float f32x4;
typedef unsigned int uint;

// ---------------- bf16 helpers ----------------

static __device__ inline float bf_lo(uint u) { return __uint_as_float(u << 16); }
static __device__ inline float bf_hi(uint u) { return __uint_as_float(u & 0xffff0000u); }

static __device__ inline uint pack_bf2(float a, float b) {
    union { __hip_bfloat16 h; unsigned short u; } ua, ub;
    ua.h = __float2bfloat16(a);
    ub.h = __float2bfloat16(b);
    return ((uint)ub.u << 16) | (uint)ua.u;
}

// ---------------- CSR construction (binned counting sort, packed uint pairs) ----------------
// packed pair: (local_key << 20) | value   (local_key <= 7 bits, value < 2^17)

__global__ void bin_scatter(const int* __restrict__ he, int* __restrict__ ccnt,
                            uint* __restrict__ pairs) {
    __shared__ int hcnt[NB_TOT];
    __shared__ int hbase[NB_TOT];
    int tid = threadIdx.x;
    int base = blockIdx.x * 8192;
    for (int j = tid; j < NB_TOT; j += 256) hcnt[j] = 0;
    __syncthreads();
    for (int k = 0; k < 32; k++) {
        int i = base + k * 256 + tid;
        if (i < NPINS) {
            int n = he[i];
            int e = he[NPINS + i];
            atomicAdd(&hcnt[e >> EB_SHIFT], 1);
            atomicAdd(&hcnt[NB_E + (n >> NB_SHIFT)], 1);
        }
    }
    __syncthreads();
    for (int j = tid; j < NB_TOT; j += 256)
        hbase[j] = hcnt[j] ? atomicAdd(&ccnt[j], hcnt[j]) : 0;
    __syncthreads();
    for (int k = 0; k < 32; k++) {
        int i = base + k * 256 + tid;
        if (i < NPINS) {
            int n = he[i];
            int e = he[NPINS + i];
            int be = e >> EB_SHIFT;
            int pe = atomicAdd(&hbase[be], 1);
            if (pe < ECAP)
                pairs[be * ECAP + pe] = ((uint)(e & 63) << 20) | (uint)n;
            int bn = n >> NB_SHIFT;
            int pn = atomicAdd(&hbase[NB_E + bn], 1);
            if (pn < NCAP)
                pairs[NB_E * ECAP + bn * NCAP + pn] = ((uint)(n & 127) << 20) | (uint)e;
        }
    }
}

// single register-staged read of pairs; LDS hist; LDS cursor placement
template <int KPB, int CAP>
__global__ void bucket_place(const uint* __restrict__ pairs, int regbase,
                             const int* __restrict__ ccnt, int cbase, int kfine_base, int nkeys,
                             int* __restrict__ off, int* __restrict__ cnt,
                             int* __restrict__ pins) {
    constexpr int NIT = CAP / 256;
    __shared__ int fh[KPB];
    __shared__ int fo[KPB];
    __shared__ int fcur[KPB];
    int b = blockIdx.x;
    int tid = threadIdx.x;
    int rb = regbase + b * CAP;
    int count = ccnt[cbase + b];
    if (count > CAP) count = CAP;
    int keyfirst = b * KPB;
    uint pr[NIT];
    for (int k = tid; k < KPB; k += 256) { fh[k] = 0; fcur[k] = 0; }
#pragma unroll
    for (int i = 0; i < NIT; i++) {
        int idx = tid + i * 256;
        if (idx < count) pr[i] = pairs[rb + idx];
    }
    __syncthreads();
#pragma unroll
    for (int i = 0; i < NIT; i++) {
        int idx = tid + i * 256;
        if (idx < count) atomicAdd(&fh[pr[i] >> 20], 1);
    }
    __syncthreads();
    if (tid == 0) {
        int run = rb;
        for (int k = 0; k < KPB; k++) { fo[k] = run; run += fh[k]; }
    }
    __syncthreads();
    for (int k = tid; k < KPB; k += 256) {
        int key = keyfirst + k;
        if (key < nkeys) { off[kfine_base + key] = fo[k]; cnt[kfine_base + key] = fh[k]; }
    }
#pragma unroll
    for (int i = 0; i < NIT; i++) {
        int idx = tid + i * 256;
        if (idx < count) {
            uint p = pr[i];
            int kl = (int)(p >> 20);
            int pos = atomicAdd(&fcur[kl], 1);
            pins[fo[kl] + pos] = (int)(p & 0xFFFFFu);
        }
    }
}

// ---------------- MFMA GEMM: Yb[nrows,COLS](bf16) = X[nrows,128] @ W[128,COLS] ----------------

template <int COLS, bool BF16IN>
__global__ void gemm_mfma(const void* __restrict__ Xv, const float* __restrict__ W,
                          unsigned short* __restrict__ Yb) {
    __shared__ __align__(16) char lds[128 * 256 + COLS * 256];
    char* Xl = lds;                 // [128 rows][128 k] bf16, XOR-swizzled
    char* Wt = lds + 128 * 256;     // [COLS cols][128 k] bf16, swizzled
    int tid = threadIdx.x;
    long rowbase = (long)blockIdx.x * 128;

    if constexpr (!BF16IN) {
        const float4* X4 = reinterpret_cast<const float4*>(Xv);
#pragma unroll
        for (int i = 0; i < 16; i++) {
            int f = tid + i * 256;
            int r = f >> 5;
            int c4 = f & 31;
            long gr = rowbase + r;
            if (gr > NNODES - 1) gr = NNODES - 1;
            float4 v = X4[gr * 32 + c4];
            uint lo = pack_bf2(v.x, v.y);
            uint hi = pack_bf2(v.z, v.w);
            int byte = r * 256 + ((c4 * 8) ^ ((r & 7) << 4));
            *reinterpret_cast<uint2*>(Xl + byte) = make_uint2(lo, hi);
        }
    } else {
        const uint4* X4 = reinterpret_cast<const uint4*>(Xv);
#pragma unroll
        for (int i = 0; i < 8; i++) {
            int f = tid + i * 256;
            int r = f >> 4;
            int c = f & 15;
            long gr = rowbase + r;
            if (gr > NNODES - 1) gr = NNODES - 1;
            uint4 v = X4[gr * 16 + c];
            int byte = r * 256 + ((c * 16) ^ ((r & 7) << 4));
            *reinterpret_cast<uint4*>(Xl + byte) = v;
        }
    }
    for (int f = tid; f < 128 * COLS / 4; f += 256) {
        int k = f / (COLS / 4);
        int c4 = f % (COLS / 4);
        float4 v = reinterpret_cast<const float4*>(W)[f];
        float vv[4] = {v.x, v.y, v.z, v.w};
#pragma unroll
        for (int j = 0; j < 4; j++) {
            int c = c4 * 4 + j;
            union { __hip_bfloat16 h; short s; } u;
            u.h = __float2bfloat16(vv[j]);
            int byte = c * 256 + ((k * 2) ^ ((c & 7) << 4));
            *reinterpret_cast<short*>(Wt + byte) = u.s;
        }
    }
    __syncthreads();

    constexpr int NF = COLS / 16;
    int wave = tid >> 6;
    int lane = tid & 63;
    int lrow = lane & 15;
    int lq = lane >> 4;
    f32x4 acc[2][NF] = {};

#pragma unroll
    for (int ks = 0; ks < 4; ks++) {
        short8 a[2];
#pragma unroll
        for (int rt = 0; rt < 2; rt++) {
            int r = wave * 32 + rt * 16 + lrow;
            int byte = r * 256 + ((ks * 64 + lq * 16) ^ ((r & 7) << 4));
            a[rt] = *reinterpret_cast<const short8*>(Xl + byte);
        }
#pragma unroll
        for (int nf = 0; nf < NF; nf++) {
            int c = nf * 16 + lrow;
            int byte = c * 256 + ((ks * 64 + lq * 16) ^ ((c & 7) << 4));
            short8 b = *reinterpret_cast<const short8*>(Wt + byte);
            acc[0][nf] = __builtin_amdgcn_mfma_f32_16x16x32_bf16(a[0], b, acc[0][nf], 0, 0, 0);
            acc[1][nf] = __builtin_amdgcn_mfma_f32_16x16x32_bf16(a[1], b, acc[1][nf], 0, 0, 0);
        }
    }

#pragma unroll
    for (int rt = 0; rt < 2; rt++)
#pragma unroll
        for (int nf = 0; nf < NF; nf++)
#pragma unroll
            for (int r = 0; r < 4; r++) {
                long row = rowbase + wave * 32 + rt * 16 + lq * 4 + r;
                if (row < NNODES) {
                    union { __hip_bfloat16 h; unsigned short u; } u;
                    u.h = __float2bfloat16(acc[rt][nf][r]);
                    Yb[row * COLS + nf * 16 + lrow] = u.u;
                }
            }
}

// ---------------- aggregation (bf16 features, fp32 accumulate, uint4 lanes) ----------------
// F=128: quarter-wave per pin (16 lanes x 16 B = 256 B row); 16-pin chunks.
// F=64:  eighth-wave per pin (8 lanes x 16 B = 128 B row); 32-pin chunks.

#define ACC_U4(u) do { \
    a0 += bf_lo((u).x); a1 += bf_hi((u).x); a2 += bf_lo((u).y); a3 += bf_hi((u).y); \
    a4 += bf_lo((u).z); a5 += bf_hi((u).z); a6 += bf_lo((u).w); a7 += bf_hi((u).w); } while (0)

#define RED2(x, o1, o2) do { x += __shfl_xor(x, o1); x += __shfl_xor(x, o2); } while (0)
#define REDQ(o1, o2) do { RED2(a0,o1,o2); RED2(a1,o1,o2); RED2(a2,o1,o2); RED2(a3,o1,o2); \
                          RED2(a4,o1,o2); RED2(a5,o1,o2); RED2(a6,o1,o2); RED2(a7,o1,o2); } while (0)

__global__ void edge_agg_128(const uint4* __restrict__ feat4, const int* __restrict__ pins,
                             const int* __restrict__ off, const int* __restrict__ cnt,
                             uint4* __restrict__ outp) {
    int s = blockIdx.x * 4 + (threadIdx.x >> 6);
    if (s >= NEDGES) return;
    int lane = threadIdx.x & 63;
    int q = lane >> 4, fp = lane & 15;
    int start = off[s], c = cnt[s];
    float a0 = 0.f, a1 = 0.f, a2 = 0.f, a3 = 0.f, a4 = 0.f, a5 = 0.f, a6 = 0.f, a7 = 0.f;
    for (int cb = 0; cb < c; cb += 64) {
        int rem = c - cb;
        int lim = rem < 64 ? rem : 64;
        int pk = 0;
        if (lane < lim) pk = pins[start + cb + lane];
        int i = 0;
        for (; i + 16 <= lim; i += 16) {
            int pa = __shfl(pk, i + q);
            int pb = __shfl(pk, i + 4 + q);
            int pc = __shfl(pk, i + 8 + q);
            int pd = __shfl(pk, i + 12 + q);
            uint4 ua = feat4[(uint)pa * 16 + fp];
            uint4 ub = feat4[(uint)pb * 16 + fp];
            uint4 uc = feat4[(uint)pc * 16 + fp];
            uint4 ud = feat4[(uint)pd * 16 + fp];
            ACC_U4(ua); ACC_U4(ub); ACC_U4(uc); ACC_U4(ud);
        }
        for (; i + 4 <= lim; i += 4) {
            int p = __shfl(pk, i + q);
            uint4 u = feat4[(uint)p * 16 + fp];
            ACC_U4(u);
        }
        if (i < lim) {
            int idx = i + q;
            int p = __shfl(pk, idx < lim ? idx : i);
            if (idx < lim) {
                uint4 u = feat4[(uint)p * 16 + fp];
                ACC_U4(u);
            }
        }
    }
    REDQ(16, 32);
    if (q == 0) {
        float inv = (c > 0) ? (1.f / (float)c) : 0.f;
        outp[(uint)s * 16 + fp] = make_uint4(pack_bf2(a0 * inv, a1 * inv),
                                             pack_bf2(a2 * inv, a3 * inv),
                                             pack_bf2(a4 * inv, a5 * inv),
                                             pack_bf2(a6 * inv, a7 * inv));
    }
}

__global__ void node_agg_ln(const uint4* __restrict__ m4, const int* __restrict__ pins,
                            const int* __restrict__ off, const int* __restrict__ cnt,
                            const float* __restrict__ b1, const float* __restrict__ gamma,
                            const float* __restrict__ beta, uint4* __restrict__ hout) {
    int s = blockIdx.x * 4 + (threadIdx.x >> 6);
    if (s >= NNODES) return;
    int lane = threadIdx.x & 63;
    int q = lane >> 4, fp = lane & 15;
    int start = off[s], c = cnt[s];
    float a0 = 0.f, a1 = 0.f, a2 = 0.f, a3 = 0.f, a4 = 0.f, a5 = 0.f, a6 = 0.f, a7 = 0.f;
    for (int cb = 0; cb < c; cb += 64) {
        int rem = c - cb;
        int lim = rem < 64 ? rem : 64;
        int pk = 0;
        if (lane < lim) pk = pins[start + cb + lane];
        int i = 0;
        for (; i + 16 <= lim; i += 16) {
            int pa = __shfl(pk, i + q);
            int pb = __shfl(pk, i + 4 + q);
            int pc = __shfl(pk, i + 8 + q);
            int pd = __shfl(pk, i + 12 + q);
            uint4 ua = m4[(uint)pa * 16 + fp];
            uint4 ub = m4[(uint)pb * 16 + fp];
            uint4 uc = m4[(uint)pc * 16 + fp];
            uint4 ud = m4[(uint)pd * 16 + fp];
            ACC_U4(ua); ACC_U4(ub); ACC_U4(uc); ACC_U4(ud);
        }
        for (; i + 4 <= lim; i += 4) {
            int p = __shfl(pk, i + q);
            uint4 u = m4[(uint)p * 16 + fp];
            ACC_U4(u);
        }
        if (i < lim) {
            int idx = i + q;
            int p = __shfl(pk, idx < lim ? idx : i);
            if (idx < lim) {
                uint4 u = m4[(uint)p * 16 + fp];
                ACC_U4(u);
            }
        }
    }
    REDQ(16, 32);
    float dinv = (c > 0) ? (1.f / (float)c) : 0.f;
    float4 bb0 = reinterpret_cast<const float4*>(b1)[fp * 2];
    float4 bb1 = reinterpret_cast<const float4*>(b1)[fp * 2 + 1];
    float v0 = a0 * dinv + bb0.x;
    float v1 = a1 * dinv + bb0.y;
    float v2 = a2 * dinv + bb0.z;
    float v3 = a3 * dinv + bb0.w;
    float v4 = a4 * dinv + bb1.x;
    float v5 = a5 * dinv + bb1.y;
    float v6 = a6 * dinv + bb1.z;
    float v7 = a7 * dinv + bb1.w;
    float sum = ((v0 + v1) + (v2 + v3)) + ((v4 + v5) + (v6 + v7));
    float sq = ((v0 * v0 + v1 * v1) + (v2 * v2 + v3 * v3)) +
               ((v4 * v4 + v5 * v5) + (v6 * v6 + v7 * v7));
#pragma unroll
    for (int o = 1; o < 16; o <<= 1) {
        sum += __shfl_xor(sum, o);
        sq  += __shfl_xor(sq, o);
    }
    float mu = sum * (1.f / 128.f);
    float var = sq * (1.f / 128.f) - mu * mu;
    float rstd = rsqrtf(var + 1e-5f);
    if (q == 0) {
        float4 g0  = reinterpret_cast<const float4*>(gamma)[fp * 2];
        float4 g1  = reinterpret_cast<const float4*>(gamma)[fp * 2 + 1];
        float4 be0 = reinterpret_cast<const float4*>(beta)[fp * 2];
        float4 be1 = reinterpret_cast<const float4*>(beta)[fp * 2 + 1];
        float h0 = (v0 - mu) * rstd * g0.x + be0.x;
        float h1 = (v1 - mu) * rstd * g0.y + be0.y;
        float h2 = (v2 - mu) * rstd * g0.z + be0.z;
        float h3 = (v3 - mu) * rstd * g0.w + be0.w;
        float h4 = (v4 - mu) * rstd * g1.x + be1.x;
        float h5 = (v5 - mu) * rstd * g1.y + be1.y;
        float h6 = (v6 - mu) * rstd * g1.z + be1.z;
        float h7 = (v7 - mu) * rstd * g1.w + be1.w;
        h0 = (h0 > 0.f) ? h0 : 0.01f * h0;
        h1 = (h1 > 0.f) ? h1 : 0.01f * h1;
        h2 = (h2 > 0.f) ? h2 : 0.01f * h2;
        h3 = (h3 > 0.f) ? h3 : 0.01f * h3;
        h4 = (h4 > 0.f) ? h4 : 0.01f * h4;
        h5 = (h5 > 0.f) ? h5 : 0.01f * h5;
        h6 = (h6 > 0.f) ? h6 : 0.01f * h6;
        h7 = (h7 > 0.f) ? h7 : 0.01f * h7;
        hout[(uint)s * 16 + fp] = make_uint4(pack_bf2(h0, h1), pack_bf2(h2, h3),
                                             pack_bf2(h4, h5), pack_bf2(h6, h7));
    }
}

#define REDE(o1, o2, o3) do { \
    a0 += __shfl_xor(a0, o1); a0 += __shfl_xor(a0, o2); a0 += __shfl_xor(a0, o3); \
    a1 += __shfl_xor(a1, o1); a1 += __shfl_xor(a1, o2); a1 += __shfl_xor(a1, o3); \
    a2 += __shfl_xor(a2, o1); a2 += __shfl_xor(a2, o2); a2 += __shfl_xor(a2, o3); \
    a3 += __shfl_xor(a3, o1); a3 += __shfl_xor(a3, o2); a3 += __shfl_xor(a3, o3); \
    a4 += __shfl_xor(a4, o1); a4 += __shfl_xor(a4, o2); a4 += __shfl_xor(a4, o3); \
    a5 += __shfl_xor(a5, o1); a5 += __shfl_xor(a5, o2); a5 += __shfl_xor(a5, o3); \
    a6 += __shfl_xor(a6, o1); a6 += __shfl_xor(a6, o2); a6 += __shfl_xor(a6, o3); \
    a7 += __shfl_xor(a7, o1); a7 += __shfl_xor(a7, o2); a7 += __shfl_xor(a7, o3); } while (0)

__global__ void edge_agg_64(const uint4* __restrict__ feat4, const int* __restrict__ pins,
                            const int* __restrict__ off, const int* __restrict__ cnt,
                            uint4* __restrict__ outp) {
    int s = blockIdx.x * 4 + (threadIdx.x >> 6);
    if (s >= NEDGES) return;
    int lane = threadIdx.x & 63;
    int e = lane >> 3, fp = lane & 7;
    int start = off[s], c = cnt[s];
    float a0 = 0.f, a1 = 0.f, a2 = 0.f, a3 = 0.f, a4 = 0.f, a5 = 0.f, a6 = 0.f, a7 = 0.f;
    for (int cb = 0; cb < c; cb += 64) {
        int rem = c - cb;
        int lim = rem < 64 ? rem : 64;
        int pk = 0;
        if (lane < lim) pk = pins[start + cb + lane];
        int i = 0;
        for (; i + 32 <= lim; i += 32) {
            int pa = __shfl(pk, i + e);
            int pb = __shfl(pk, i + 8 + e);
            int pc = __shfl(pk, i + 16 + e);
            int pd = __shfl(pk, i + 24 + e);
            uint4 ua = feat4[(uint)pa * 8 + fp];
            uint4 ub = feat4[(uint)pb * 8 + fp];
            uint4 uc = feat4[(uint)pc * 8 + fp];
            uint4 ud = feat4[(uint)pd * 8 + fp];
            ACC_U4(ua); ACC_U4(ub); ACC_U4(uc); ACC_U4(ud);
        }
        for (; i + 8 <= lim; i += 8) {
            int p = __shfl(pk, i + e);
            uint4 u = feat4[(uint)p * 8 + fp];
            ACC_U4(u);
        }
        if (i < lim) {
            int idx = i + e;
            int p = __shfl(pk, idx < lim ? idx : i);
            if (idx < lim) {
                uint4 u = feat4[(uint)p * 8 + fp];
                ACC_U4(u);
            }
        }
    }
    REDE(8, 16, 32);
    if (e == 0) {
        float inv = (c > 0) ? (1.f / (float)c) : 0.f;
        outp[(uint)s * 8 + fp] = make_uint4(pack_bf2(a0 * inv, a1 * inv),
                                            pack_bf2(a2 * inv, a3 * inv),
                                            pack_bf2(a4 * inv, a5 * inv),
                                            pack_bf2(a6 * inv, a7 * inv));
    }
}

__global__ void node_agg_out(const uint4* __restrict__ m4, const int* __restrict__ pins,
                             const int* __restrict__ off, const int* __restrict__ cnt,
                             const float* __restrict__ b3, float4* __restrict__ out4) {
    int s = blockIdx.x * 4 + (threadIdx.x >> 6);
    if (s >= NNODES) return;
    int lane = threadIdx.x & 63;
    int e = lane >> 3, fp = lane & 7;
    int start = off[s], c = cnt[s];
    float a0 = 0.f, a1 = 0.f, a2 = 0.f, a3 = 0.f, a4 = 0.f, a5 = 0.f, a6 = 0.f, a7 = 0.f;
    for (int cb = 0; cb < c; cb += 64) {
        int rem = c - cb;
        int lim = rem < 64 ? rem : 64;
        int pk = 0;
        if (lane < lim) pk = pins[start + cb + lane];
        int i = 0;
        for (; i + 32 <= lim; i += 32) {
            int pa = __shfl(pk, i + e);
            int pb = __shfl(pk, i + 8 + e);
            int pc = __shfl(pk, i + 16 + e);
            int pd = __shfl(pk, i + 24 + e);
            uint4 ua = m4[(uint)pa * 8 + fp];
            uint4 ub = m4[(uint)pb * 8 + fp];
            uint4 uc = m4[(uint)pc * 8 + fp];
            uint4 ud = m4[(uint)pd * 8 + fp];
            ACC_U4(ua); ACC_U4(ub); ACC_U4(uc); ACC_U4(ud);
        }
        for (; i + 8 <= lim; i += 8) {
            int p = __shfl(pk, i + e);
            uint4 u = m4[(uint)p * 8 + fp];
            ACC_U4(u);
        }
        if (i < lim) {
            int idx = i + e;
            int p = __shfl(pk, idx < lim ? idx : i);
            if (idx < lim) {
                uint4 u = m4[(uint)p * 8 + fp];
                ACC_U4(u);
            }
        }
    }
    REDE(8, 16, 32);
    if (e == 0) {
        float inv = (c > 0) ? (1.f / (float)c) : 0.f;
        float4 bb0 = reinterpret_cast<const float4*>(b3)[fp * 2];
        float4 bb1 = reinterpret_cast<const float4*>(b3)[fp * 2 + 1];
        out4[(uint)s * 16 + fp * 2] = make_float4(a0 * inv + bb0.x, a1 * inv + bb0.y,
                                                  a2 * inv + bb0.z, a3 * inv + bb0.w);
        out4[(uint)s * 16 + fp * 2 + 1] = make_float4(a4 * inv + bb1.x, a5 * inv + bb1.y,
                                                      a6 * inv + bb1.z, a7 * inv + bb1.w);
    }
}

// ---------------- launch ----------------

extern "C" void kernel_launch(void* const* d_in, const int* in_sizes, int n_in,
                              void* d_out, int out_size, void* d_ws, size_t ws_size,
                              hipStream_t stream) {
    const float* x     = (const float*)d_in[0];
    const int*   he    = (const int*)d_in[1];
    const float* W1    = (const float*)d_in[2];
    const float* b1    = (const float*)d_in[3];
    const float* gamma = (const float*)d_in[4];
    const float* beta  = (const float*)d_in[5];
    const float* W3    = (const float*)d_in[6];
    const float* b3    = (const float*)d_in[7];
    float* out = (float*)d_out;

    char* ws = (char*)d_ws;
    uint* xWb = (uint*)ws;                                  // 25.6 MB bf16 (hWb 12.8 MB overlay)
    uint* mb  = (uint*)(ws + 25600000);                     // 5.12 MB bf16 (m2b 2.56 MB overlay)
    uint* hb  = (uint*)(ws + 25600000 + 5120000);           // 25.6 MB bf16
    char* ip  = ws + 25600000 + 5120000 + 25600000;
    int* off  = (int*)ip;                   // NEDGES+NNODES
    int* cnt  = off + (NEDGES + NNODES);
    int* ccnt = cnt + (NEDGES + NNODES);    // NB_TOT
    int* pins = ccnt + NB_TOT + 64;         // REG_TOTAL ints
    uint* pairs = (uint*)ws;                // 15.7 MB overlay, dead before gemm1

    const int nblkA = (NPINS + 8191) / 8192;   // 196
    const int ngemm = (NNODES + 127) / 128;    // 782

    hipMemsetAsync(ccnt, 0, sizeof(int) * NB_TOT, stream);
    bin_scatter<<<nblkA, 256, 0, stream>>>(he, ccnt, pairs);
    bucket_place<64, ECAP><<<NB_E, 256, 0, stream>>>(pairs, 0, ccnt, 0, 0, NEDGES,
                                                     off, cnt, pins);
    bucket_place<128, NCAP><<<NB_N, 256, 0, stream>>>(pairs, NB_E * ECAP, ccnt, NB_E,
                                                      NEDGES, NNODES, off, cnt, pins);

    // conv1: xWb = bf16(x @ W1); edge agg; node agg + LN + LReLU -> hb
    gemm_mfma<128, false><<<ngemm, 256, 0, stream>>>(x, W1, (unsigned short*)xWb);
    edge_agg_128<<<(NEDGES + 3) / 4, 256, 0, stream>>>((const uint4*)xWb, pins, off, cnt,
                                                       (uint4*)mb);
    node_agg_ln<<<(NNODES + 3) / 4, 256, 0, stream>>>((const uint4*)mb, pins, off + NEDGES,
                                                      cnt + NEDGES, b1, gamma, beta,
                                                      (uint4*)hb);
    // conv2: hWb = bf16(h @ W3) (reuse xWb); edge agg (reuse mb); node agg -> out
    gemm_mfma<64, true><<<ngemm, 256, 0, stream>>>(hb, W3, (unsigned short*)xWb);
    edge_agg_64<<<(NEDGES + 3) / 4, 256, 0, stream>>>((const uint4*)xWb, pins, off, cnt,
                                                      (uint4*)mb);
    node_agg_out<<<(NNODES + 3) / 4, 256, 0, stream>>>((const uint4*)mb, pins, off + NEDGES,
                                                       cnt + NEDGES, b3, (float4*)out);
}

// Round 11
// 276.802 us; speedup vs baseline: 1.1732x; 1.0513x over previous
//
#include <hip/hip_runtime.h>
#include <hip/hip_bf16.h>

#define NNODES 100000
#define NEDGES 20000
#define NPINS  1600000

#define EB_SHIFT 6
#define NB_SHIFT 7
#define NB_E ((NEDGES + 63) / 64)      // 313
#define NB_N ((NNODES + 127) / 128)    // 782
#define NB_TOT (NB_E + NB_N)           // 1095
#define ECAP 6144
#define NCAP 2560
#define REG_TOTAL (NB_E * ECAP + NB_N * NCAP)   // 3,924,992

typedef __attribute__((ext_vector_type(8))) short short8;
typedef __attribute__((ext_vector_type(4))) float f32x4;
typedef unsigned int uint;

// ---------------- bf16 helpers ----------------

static __device__ inline float bf_lo(uint u) { return __uint_as_float(u << 16); }
static __device__ inline float bf_hi(uint u) { return __uint_as_float(u & 0xffff0000u); }

static __device__ inline uint pack_bf2(float a, float b) {
    union { __hip_bfloat16 h; unsigned short u; } ua, ub;
    ua.h = __float2bfloat16(a);
    ub.h = __float2bfloat16(b);
    return ((uint)ub.u << 16) | (uint)ua.u;
}

// ---------------- GEMM device body: Yb[nrows,COLS](bf16) = X @ W ----------------

template <int COLS, bool BF16IN>
static __device__ __forceinline__ void gemm_body(const void* __restrict__ Xv,
                                                 const float* __restrict__ W,
                                                 unsigned short* __restrict__ Yb,
                                                 long rowbase, char* lds) {
    char* Xl = lds;                 // [128 rows][128 k] bf16, XOR-swizzled
    char* Wt = lds + 128 * 256;     // [COLS cols][128 k] bf16, swizzled
    int tid = threadIdx.x;

    if constexpr (!BF16IN) {
        const float4* X4 = reinterpret_cast<const float4*>(Xv);
#pragma unroll
        for (int i = 0; i < 16; i++) {
            int f = tid + i * 256;
            int r = f >> 5;
            int c4 = f & 31;
            long gr = rowbase + r;
            if (gr > NNODES - 1) gr = NNODES - 1;
            float4 v = X4[gr * 32 + c4];
            uint lo = pack_bf2(v.x, v.y);
            uint hi = pack_bf2(v.z, v.w);
            int byte = r * 256 + ((c4 * 8) ^ ((r & 7) << 4));
            *reinterpret_cast<uint2*>(Xl + byte) = make_uint2(lo, hi);
        }
    } else {
        const uint4* X4 = reinterpret_cast<const uint4*>(Xv);
#pragma unroll
        for (int i = 0; i < 8; i++) {
            int f = tid + i * 256;
            int r = f >> 4;
            int c = f & 15;
            long gr = rowbase + r;
            if (gr > NNODES - 1) gr = NNODES - 1;
            uint4 v = X4[gr * 16 + c];
            int byte = r * 256 + ((c * 16) ^ ((r & 7) << 4));
            *reinterpret_cast<uint4*>(Xl + byte) = v;
        }
    }
    for (int f = tid; f < 128 * COLS / 4; f += 256) {
        int k = f / (COLS / 4);
        int c4 = f % (COLS / 4);
        float4 v = reinterpret_cast<const float4*>(W)[f];
        float vv[4] = {v.x, v.y, v.z, v.w};
#pragma unroll
        for (int j = 0; j < 4; j++) {
            int c = c4 * 4 + j;
            union { __hip_bfloat16 h; short s; } u;
            u.h = __float2bfloat16(vv[j]);
            int byte = c * 256 + ((k * 2) ^ ((c & 7) << 4));
            *reinterpret_cast<short*>(Wt + byte) = u.s;
        }
    }
    __syncthreads();

    constexpr int NF = COLS / 16;
    int wave = tid >> 6;
    int lane = tid & 63;
    int lrow = lane & 15;
    int lq = lane >> 4;
    f32x4 acc[2][NF] = {};

#pragma unroll
    for (int ks = 0; ks < 4; ks++) {
        short8 a[2];
#pragma unroll
        for (int rt = 0; rt < 2; rt++) {
            int r = wave * 32 + rt * 16 + lrow;
            int byte = r * 256 + ((ks * 64 + lq * 16) ^ ((r & 7) << 4));
            a[rt] = *reinterpret_cast<const short8*>(Xl + byte);
        }
#pragma unroll
        for (int nf = 0; nf < NF; nf++) {
            int c = nf * 16 + lrow;
            int byte = c * 256 + ((ks * 64 + lq * 16) ^ ((c & 7) << 4));
            short8 b = *reinterpret_cast<const short8*>(Wt + byte);
            acc[0][nf] = __builtin_amdgcn_mfma_f32_16x16x32_bf16(a[0], b, acc[0][nf], 0, 0, 0);
            acc[1][nf] = __builtin_amdgcn_mfma_f32_16x16x32_bf16(a[1], b, acc[1][nf], 0, 0, 0);
        }
    }

#pragma unroll
    for (int rt = 0; rt < 2; rt++)
#pragma unroll
        for (int nf = 0; nf < NF; nf++)
#pragma unroll
            for (int r = 0; r < 4; r++) {
                long row = rowbase + wave * 32 + rt * 16 + lq * 4 + r;
                if (row < NNODES) {
                    union { __hip_bfloat16 h; unsigned short u; } u;
                    u.h = __float2bfloat16(acc[rt][nf][r]);
                    Yb[row * COLS + nf * 16 + lrow] = u.u;
                }
            }
}

// ---------------- bin_scatter device body ----------------
// packed pair: (local_key << 20) | value

static __device__ __forceinline__ void scatter_body(const int* __restrict__ he,
                                                    int* __restrict__ ccnt,
                                                    uint* __restrict__ pairs,
                                                    int sb, int* hcnt, int* hbase) {
    int tid = threadIdx.x;
    int base = sb * 8192;
    for (int j = tid; j < NB_TOT; j += 256) hcnt[j] = 0;
    __syncthreads();
    for (int k = 0; k < 32; k++) {
        int i = base + k * 256 + tid;
        if (i < NPINS) {
            int n = he[i];
            int e = he[NPINS + i];
            atomicAdd(&hcnt[e >> EB_SHIFT], 1);
            atomicAdd(&hcnt[NB_E + (n >> NB_SHIFT)], 1);
        }
    }
    __syncthreads();
    for (int j = tid; j < NB_TOT; j += 256)
        hbase[j] = hcnt[j] ? atomicAdd(&ccnt[j], hcnt[j]) : 0;
    __syncthreads();
    for (int k = 0; k < 32; k++) {
        int i = base + k * 256 + tid;
        if (i < NPINS) {
            int n = he[i];
            int e = he[NPINS + i];
            int be = e >> EB_SHIFT;
            int pe = atomicAdd(&hbase[be], 1);
            if (pe < ECAP)
                pairs[be * ECAP + pe] = ((uint)(e & 63) << 20) | (uint)n;
            int bn = n >> NB_SHIFT;
            int pn = atomicAdd(&hbase[NB_E + bn], 1);
            if (pn < NCAP)
                pairs[NB_E * ECAP + bn * NCAP + pn] = ((uint)(n & 127) << 20) | (uint)e;
        }
    }
}

// K1: gemm1 (784 slots, 782 used) interleaved with bin_scatter (196 slots, every 5th block)
__global__ void k1_gemm_scatter(const float* __restrict__ x, const float* __restrict__ W1,
                                unsigned short* __restrict__ xWb, const int* __restrict__ he,
                                int* __restrict__ ccnt, uint* __restrict__ pairs) {
    __shared__ __align__(16) char lds[128 * 256 + 128 * 256];  // 64 KB
    int b = blockIdx.x;
    if (b % 5 == 4) {
        int* hcnt = (int*)lds;
        scatter_body(he, ccnt, pairs, b / 5, hcnt, hcnt + NB_TOT);
    } else {
        int g = b - (b + 1) / 5;
        if (g < (NNODES + 127) / 128)
            gemm_body<128, false>(x, W1, xWb, (long)g * 128, lds);
    }
}

// standalone gemm2
__global__ void gemm2_kernel(const void* __restrict__ Xv, const float* __restrict__ W,
                             unsigned short* __restrict__ Yb) {
    __shared__ __align__(16) char lds[128 * 256 + 64 * 256];
    gemm_body<64, true>(Xv, W, Yb, (long)blockIdx.x * 128, lds);
}

// ---------------- K2: fused bucket_place (edge + node) ----------------

template <int KPB, int CAP>
static __device__ __forceinline__ void place_body(const uint* __restrict__ pairs, int regbase,
                                                  const int* __restrict__ ccnt, int cbase,
                                                  int kfine_base, int nkeys,
                                                  int* __restrict__ off, int* __restrict__ cnt,
                                                  int* __restrict__ pins, int b,
                                                  int* fh, int* fo, int* fcur) {
    constexpr int NIT = CAP / 256;
    int tid = threadIdx.x;
    int rb = regbase + b * CAP;
    int count = ccnt[cbase + b];
    if (count > CAP) count = CAP;
    int keyfirst = b * KPB;
    uint pr[NIT];
    for (int k = tid; k < KPB; k += 256) { fh[k] = 0; fcur[k] = 0; }
#pragma unroll
    for (int i = 0; i < NIT; i++) {
        int idx = tid + i * 256;
        if (idx < count) pr[i] = pairs[rb + idx];
    }
    __syncthreads();
#pragma unroll
    for (int i = 0; i < NIT; i++) {
        int idx = tid + i * 256;
        if (idx < count) atomicAdd(&fh[pr[i] >> 20], 1);
    }
    __syncthreads();
    if (tid == 0) {
        int run = rb;
        for (int k = 0; k < KPB; k++) { fo[k] = run; run += fh[k]; }
    }
    __syncthreads();
    for (int k = tid; k < KPB; k += 256) {
        int key = keyfirst + k;
        if (key < nkeys) { off[kfine_base + key] = fo[k]; cnt[kfine_base + key] = fh[k]; }
    }
#pragma unroll
    for (int i = 0; i < NIT; i++) {
        int idx = tid + i * 256;
        if (idx < count) {
            uint p = pr[i];
            int kl = (int)(p >> 20);
            int pos = atomicAdd(&fcur[kl], 1);
            pins[fo[kl] + pos] = (int)(p & 0xFFFFFu);
        }
    }
}

__global__ void k2_place(const uint* __restrict__ pairs, const int* __restrict__ ccnt,
                         int* __restrict__ off, int* __restrict__ cnt,
                         int* __restrict__ pins) {
    __shared__ int fh[128], fo[128], fcur[128];
    int b = blockIdx.x;
    if (b < NB_E)
        place_body<64, ECAP>(pairs, 0, ccnt, 0, 0, NEDGES, off, cnt, pins, b, fh, fo, fcur);
    else
        place_body<128, NCAP>(pairs, NB_E * ECAP, ccnt, NB_E, NEDGES, NNODES, off, cnt, pins,
                              b - NB_E, fh, fo, fcur);
}

// ---------------- aggregation (bf16 features, fp32 accumulate, uint4 lanes) ----------------

#define ACC_U4(u) do { \
    a0 += bf_lo((u).x); a1 += bf_hi((u).x); a2 += bf_lo((u).y); a3 += bf_hi((u).y); \
    a4 += bf_lo((u).z); a5 += bf_hi((u).z); a6 += bf_lo((u).w); a7 += bf_hi((u).w); } while (0)

#define RED2(x, o1, o2) do { x += __shfl_xor(x, o1); x += __shfl_xor(x, o2); } while (0)
#define REDQ(o1, o2) do { RED2(a0,o1,o2); RED2(a1,o1,o2); RED2(a2,o1,o2); RED2(a3,o1,o2); \
                          RED2(a4,o1,o2); RED2(a5,o1,o2); RED2(a6,o1,o2); RED2(a7,o1,o2); } while (0)

__global__ void edge_agg_128(const uint4* __restrict__ feat4, const int* __restrict__ pins,
                             const int* __restrict__ off, const int* __restrict__ cnt,
                             uint4* __restrict__ outp) {
    int s = blockIdx.x * 4 + (threadIdx.x >> 6);
    if (s >= NEDGES) return;
    int lane = threadIdx.x & 63;
    int q = lane >> 4, fp = lane & 15;
    int start = off[s], c = cnt[s];
    float a0 = 0.f, a1 = 0.f, a2 = 0.f, a3 = 0.f, a4 = 0.f, a5 = 0.f, a6 = 0.f, a7 = 0.f;
    for (int cb = 0; cb < c; cb += 64) {
        int rem = c - cb;
        int lim = rem < 64 ? rem : 64;
        int pk = 0;
        if (lane < lim) pk = pins[start + cb + lane];
        int i = 0;
        for (; i + 16 <= lim; i += 16) {
            int pa = __shfl(pk, i + q);
            int pb = __shfl(pk, i + 4 + q);
            int pc = __shfl(pk, i + 8 + q);
            int pd = __shfl(pk, i + 12 + q);
            uint4 ua = feat4[(uint)pa * 16 + fp];
            uint4 ub = feat4[(uint)pb * 16 + fp];
            uint4 uc = feat4[(uint)pc * 16 + fp];
            uint4 ud = feat4[(uint)pd * 16 + fp];
            ACC_U4(ua); ACC_U4(ub); ACC_U4(uc); ACC_U4(ud);
        }
        for (; i + 4 <= lim; i += 4) {
            int p = __shfl(pk, i + q);
            uint4 u = feat4[(uint)p * 16 + fp];
            ACC_U4(u);
        }
        if (i < lim) {
            int idx = i + q;
            int p = __shfl(pk, idx < lim ? idx : i);
            if (idx < lim) {
                uint4 u = feat4[(uint)p * 16 + fp];
                ACC_U4(u);
            }
        }
    }
    REDQ(16, 32);
    if (q == 0) {
        float inv = (c > 0) ? (1.f / (float)c) : 0.f;
        outp[(uint)s * 16 + fp] = make_uint4(pack_bf2(a0 * inv, a1 * inv),
                                             pack_bf2(a2 * inv, a3 * inv),
                                             pack_bf2(a4 * inv, a5 * inv),
                                             pack_bf2(a6 * inv, a7 * inv));
    }
}

__global__ void node_agg_ln(const uint4* __restrict__ m4, const int* __restrict__ pins,
                            const int* __restrict__ off, const int* __restrict__ cnt,
                            const float* __restrict__ b1, const float* __restrict__ gamma,
                            const float* __restrict__ beta, uint4* __restrict__ hout) {
    int s = blockIdx.x * 4 + (threadIdx.x >> 6);
    if (s >= NNODES) return;
    int lane = threadIdx.x & 63;
    int q = lane >> 4, fp = lane & 15;
    int start = off[s], c = cnt[s];
    float a0 = 0.f, a1 = 0.f, a2 = 0.f, a3 = 0.f, a4 = 0.f, a5 = 0.f, a6 = 0.f, a7 = 0.f;
    for (int cb = 0; cb < c; cb += 64) {
        int rem = c - cb;
        int lim = rem < 64 ? rem : 64;
        int pk = 0;
        if (lane < lim) pk = pins[start + cb + lane];
        int i = 0;
        for (; i + 16 <= lim; i += 16) {
            int pa = __shfl(pk, i + q);
            int pb = __shfl(pk, i + 4 + q);
            int pc = __shfl(pk, i + 8 + q);
            int pd = __shfl(pk, i + 12 + q);
            uint4 ua = m4[(uint)pa * 16 + fp];
            uint4 ub = m4[(uint)pb * 16 + fp];
            uint4 uc = m4[(uint)pc * 16 + fp];
            uint4 ud = m4[(uint)pd * 16 + fp];
            ACC_U4(ua); ACC_U4(ub); ACC_U4(uc); ACC_U4(ud);
        }
        for (; i + 4 <= lim; i += 4) {
            int p = __shfl(pk, i + q);
            uint4 u = m4[(uint)p * 16 + fp];
            ACC_U4(u);
        }
        if (i < lim) {
            int idx = i + q;
            int p = __shfl(pk, idx < lim ? idx : i);
            if (idx < lim) {
                uint4 u = m4[(uint)p * 16 + fp];
                ACC_U4(u);
            }
        }
    }
    REDQ(16, 32);
    float dinv = (c > 0) ? (1.f / (float)c) : 0.f;
    float4 bb0 = reinterpret_cast<const float4*>(b1)[fp * 2];
    float4 bb1 = reinterpret_cast<const float4*>(b1)[fp * 2 + 1];
    float v0 = a0 * dinv + bb0.x;
    float v1 = a1 * dinv + bb0.y;
    float v2 = a2 * dinv + bb0.z;
    float v3 = a3 * dinv + bb0.w;
    float v4 = a4 * dinv + bb1.x;
    float v5 = a5 * dinv + bb1.y;
    float v6 = a6 * dinv + bb1.z;
    float v7 = a7 * dinv + bb1.w;
    float sum = ((v0 + v1) + (v2 + v3)) + ((v4 + v5) + (v6 + v7));
    float sq = ((v0 * v0 + v1 * v1) + (v2 * v2 + v3 * v3)) +
               ((v4 * v4 + v5 * v5) + (v6 * v6 + v7 * v7));
#pragma unroll
    for (int o = 1; o < 16; o <<= 1) {
        sum += __shfl_xor(sum, o);
        sq  += __shfl_xor(sq, o);
    }
    float mu = sum * (1.f / 128.f);
    float var = sq * (1.f / 128.f) - mu * mu;
    float rstd = rsqrtf(var + 1e-5f);
    if (q == 0) {
        float4 g0  = reinterpret_cast<const float4*>(gamma)[fp * 2];
        float4 g1  = reinterpret_cast<const float4*>(gamma)[fp * 2 + 1];
        float4 be0 = reinterpret_cast<const float4*>(beta)[fp * 2];
        float4 be1 = reinterpret_cast<const float4*>(beta)[fp * 2 + 1];
        float h0 = (v0 - mu) * rstd * g0.x + be0.x;
        float h1 = (v1 - mu) * rstd * g0.y + be0.y;
        float h2 = (v2 - mu) * rstd * g0.z + be0.z;
        float h3 = (v3 - mu) * rstd * g0.w + be0.w;
        float h4 = (v4 - mu) * rstd * g1.x + be1.x;
        float h5 = (v5 - mu) * rstd * g1.y + be1.y;
        float h6 = (v6 - mu) * rstd * g1.z + be1.z;
        float h7 = (v7 - mu) * rstd * g1.w + be1.w;
        h0 = (h0 > 0.f) ? h0 : 0.01f * h0;
        h1 = (h1 > 0.f) ? h1 : 0.01f * h1;
        h2 = (h2 > 0.f) ? h2 : 0.01f * h2;
        h3 = (h3 > 0.f) ? h3 : 0.01f * h3;
        h4 = (h4 > 0.f) ? h4 : 0.01f * h4;
        h5 = (h5 > 0.f) ? h5 : 0.01f * h5;
        h6 = (h6 > 0.f) ? h6 : 0.01f * h6;
        h7 = (h7 > 0.f) ? h7 : 0.01f * h7;
        hout[(uint)s * 16 + fp] = make_uint4(pack_bf2(h0, h1), pack_bf2(h2, h3),
                                             pack_bf2(h4, h5), pack_bf2(h6, h7));
    }
}

#define REDE(o1, o2, o3) do { \
    a0 += __shfl_xor(a0, o1); a0 += __shfl_xor(a0, o2); a0 += __shfl_xor(a0, o3); \
    a1 += __shfl_xor(a1, o1); a1 += __shfl_xor(a1, o2); a1 += __shfl_xor(a1, o3); \
    a2 += __shfl_xor(a2, o1); a2 += __shfl_xor(a2, o2); a2 += __shfl_xor(a2, o3); \
    a3 += __shfl_xor(a3, o1); a3 += __shfl_xor(a3, o2); a3 += __shfl_xor(a3, o3); \
    a4 += __shfl_xor(a4, o1); a4 += __shfl_xor(a4, o2); a4 += __shfl_xor(a4, o3); \
    a5 += __shfl_xor(a5, o1); a5 += __shfl_xor(a5, o2); a5 += __shfl_xor(a5, o3); \
    a6 += __shfl_xor(a6, o1); a6 += __shfl_xor(a6, o2); a6 += __shfl_xor(a6, o3); \
    a7 += __shfl_xor(a7, o1); a7 += __shfl_xor(a7, o2); a7 += __shfl_xor(a7, o3); } while (0)

__global__ void edge_agg_64(const uint4* __restrict__ feat4, const int* __restrict__ pins,
                            const int* __restrict__ off, const int* __restrict__ cnt,
                            uint4* __restrict__ outp) {
    int s = blockIdx.x * 4 + (threadIdx.x >> 6);
    if (s >= NEDGES) return;
    int lane = threadIdx.x & 63;
    int e = lane >> 3, fp = lane & 7;
    int start = off[s], c = cnt[s];
    float a0 = 0.f, a1 = 0.f, a2 = 0.f, a3 = 0.f, a4 = 0.f, a5 = 0.f, a6 = 0.f, a7 = 0.f;
    for (int cb = 0; cb < c; cb += 64) {
        int rem = c - cb;
        int lim = rem < 64 ? rem : 64;
        int pk = 0;
        if (lane < lim) pk = pins[start + cb + lane];
        int i = 0;
        for (; i + 32 <= lim; i += 32) {
            int pa = __shfl(pk, i + e);
            int pb = __shfl(pk, i + 8 + e);
            int pc = __shfl(pk, i + 16 + e);
            int pd = __shfl(pk, i + 24 + e);
            uint4 ua = feat4[(uint)pa * 8 + fp];
            uint4 ub = feat4[(uint)pb * 8 + fp];
            uint4 uc = feat4[(uint)pc * 8 + fp];
            uint4 ud = feat4[(uint)pd * 8 + fp];
            ACC_U4(ua); ACC_U4(ub); ACC_U4(uc); ACC_U4(ud);
        }
        for (; i + 8 <= lim; i += 8) {
            int p = __shfl(pk, i + e);
            uint4 u = feat4[(uint)p * 8 + fp];
            ACC_U4(u);
        }
        if (i < lim) {
            int idx = i + e;
            int p = __shfl(pk, idx < lim ? idx : i);
            if (idx < lim) {
                uint4 u = feat4[(uint)p * 8 + fp];
                ACC_U4(u);
            }
        }
    }
    REDE(8, 16, 32);
    if (e == 0) {
        float inv = (c > 0) ? (1.f / (float)c) : 0.f;
        outp[(uint)s * 8 + fp] = make_uint4(pack_bf2(a0 * inv, a1 * inv),
                                            pack_bf2(a2 * inv, a3 * inv),
                                            pack_bf2(a4 * inv, a5 * inv),
                                            pack_bf2(a6 * inv, a7 * inv));
    }
}

__global__ void node_agg_out(const uint4* __restrict__ m4, const int* __restrict__ pins,
                             const int* __restrict__ off, const int* __restrict__ cnt,
                             const float* __restrict__ b3, float4* __restrict__ out4) {
    int s = blockIdx.x * 4 + (threadIdx.x >> 6);
    if (s >= NNODES) return;
    int lane = threadIdx.x & 63;
    int e = lane >> 3, fp = lane & 7;
    int start = off[s], c = cnt[s];
    float a0 = 0.f, a1 = 0.f, a2 = 0.f, a3 = 0.f, a4 = 0.f, a5 = 0.f, a6 = 0.f, a7 = 0.f;
    for (int cb = 0; cb < c; cb += 64) {
        int rem = c - cb;
        int lim = rem < 64 ? rem : 64;
        int pk = 0;
        if (lane < lim) pk = pins[start + cb + lane];
        int i = 0;
        for (; i + 32 <= lim; i += 32) {
            int pa = __shfl(pk, i + e);
            int pb = __shfl(pk, i + 8 + e);
            int pc = __shfl(pk, i + 16 + e);
            int pd = __shfl(pk, i + 24 + e);
            uint4 ua = m4[(uint)pa * 8 + fp];
            uint4 ub = m4[(uint)pb * 8 + fp];
            uint4 uc = m4[(uint)pc * 8 + fp];
            uint4 ud = m4[(uint)pd * 8 + fp];
            ACC_U4(ua); ACC_U4(ub); ACC_U4(uc); ACC_U4(ud);
        }
        for (; i + 8 <= lim; i += 8) {
            int p = __shfl(pk, i + e);
            uint4 u = m4[(uint)p * 8 + fp];
            ACC_U4(u);
        }
        if (i < lim) {
            int idx = i + e;
            int p = __shfl(pk, idx < lim ? idx : i);
            if (idx < lim) {
                uint4 u = m4[(uint)p * 8 + fp];
                ACC_U4(u);
            }
        }
    }
    REDE(8, 16, 32);
    if (e == 0) {
        float inv = (c > 0) ? (1.f / (float)c) : 0.f;
        float4 bb0 = reinterpret_cast<const float4*>(b3)[fp * 2];
        float4 bb1 = reinterpret_cast<const float4*>(b3)[fp * 2 + 1];
        out4[(uint)s * 16 + fp * 2] = make_float4(a0 * inv + bb0.x, a1 * inv + bb0.y,
                                                  a2 * inv + bb0.z, a3 * inv + bb0.w);
        out4[(uint)s * 16 + fp * 2 + 1] = make_float4(a4 * inv + bb1.x, a5 * inv + bb1.y,
                                                      a6 * inv + bb1.z, a7 * inv + bb1.w);
    }
}

// ---------------- launch ----------------

extern "C" void kernel_launch(void* const* d_in, const int* in_sizes, int n_in,
                              void* d_out, int out_size, void* d_ws, size_t ws_size,
                              hipStream_t stream) {
    const float* x     = (const float*)d_in[0];
    const int*   he    = (const int*)d_in[1];
    const float* W1    = (const float*)d_in[2];
    const float* b1    = (const float*)d_in[3];
    const float* gamma = (const float*)d_in[4];
    const float* beta  = (const float*)d_in[5];
    const float* W3    = (const float*)d_in[6];
    const float* b3    = (const float*)d_in[7];
    float* out = (float*)d_out;

    char* ws = (char*)d_ws;
    uint* xWb = (uint*)ws;                          // 25.6 MB bf16 (hWb 12.8 MB reuse)
    uint* mb  = (uint*)(ws + 25600000);             // 5.12 MB bf16 (m2b 2.56 MB reuse)
    uint* hb  = (uint*)(ws + 30720000);             // 25.6 MB bf16
    char* ip  = ws + 56320000;
    int* off  = (int*)ip;                           // NEDGES+NNODES
    int* cnt  = off + (NEDGES + NNODES);
    int* ccnt = cnt + (NEDGES + NNODES);            // NB_TOT
    int* pins = ccnt + NB_TOT + 64;                 // REG_TOTAL ints, ends ~73.0 MB
    uint* pairs = (uint*)(ws + 73400000);           // 15.7 MB, NOT overlapping xWb (K1 runs both)

    hipMemsetAsync(ccnt, 0, sizeof(int) * NB_TOT, stream);
    // K1: gemm1 (782 blocks) || bin_scatter (196 blocks), interleaved every 5th
    k1_gemm_scatter<<<980, 256, 0, stream>>>(x, W1, (unsigned short*)xWb, he, ccnt, pairs);
    // K2: both bucket_place halves
    k2_place<<<NB_TOT, 256, 0, stream>>>(pairs, ccnt, off, cnt, pins);

    // conv1: edge agg; node agg + LN + LReLU -> hb
    edge_agg_128<<<(NEDGES + 3) / 4, 256, 0, stream>>>((const uint4*)xWb, pins, off, cnt,
                                                       (uint4*)mb);
    node_agg_ln<<<(NNODES + 3) / 4, 256, 0, stream>>>((const uint4*)mb, pins, off + NEDGES,
                                                      cnt + NEDGES, b1, gamma, beta,
                                                      (uint4*)hb);
    // conv2: hWb = bf16(h @ W3) (reuse xWb); edge agg (reuse mb); node agg -> out
    gemm2_kernel<<<(NNODES + 127) / 128, 256, 0, stream>>>(hb, W3, (unsigned short*)xWb);
    edge_agg_64<<<(NEDGES + 3) / 4, 256, 0, stream>>>((const uint4*)xWb, pins, off, cnt,
                                                      (uint4*)mb);
    node_agg_out<<<(NNODES + 3) / 4, 256, 0, stream>>>((const uint4*)mb, pins, off + NEDGES,
                                                       cnt + NEDGES, b3, (float4*)out);
}